// Round 12
// baseline (51.984 us; speedup 1.0000x reference)
//
#include <hip/hip_runtime.h>

typedef __attribute__((ext_vector_type(8))) short bf16x8;   // 8 bf16 (4 VGPRs)
typedef __attribute__((ext_vector_type(4))) float f32x4;

__device__ inline unsigned short f2bf(float f) {
  unsigned int u = __builtin_bit_cast(unsigned int, f);
  u += 0x7fffu + ((u >> 16) & 1u);     // round-to-nearest-even
  return (unsigned short)(u >> 16);
}

__device__ inline void gload16(const void* g, void* l) {
  __builtin_amdgcn_global_load_lds(
      (const __attribute__((address_space(1))) void*)g,
      (__attribute__((address_space(3))) void*)l, 16, 0, 0);
}

// C (512x256): bf16 copy pre-XOR-swizzled within each 128B sub-block of the
// 512B row (byte ^= (row&7)<<4) + exact fp32 csq. One wave per row. [r9/r11]
__global__ void prep_c(const float* __restrict__ C, unsigned short* __restrict__ Cbf,
                       float* __restrict__ csq, int K) {
  const int w = threadIdx.x >> 6, lane = threadIdx.x & 63;
  const int row = blockIdx.x * 4 + w;
  if (row >= K) return;
  const float4 v = *reinterpret_cast<const float4*>(&C[(size_t)row * 256 + lane * 4]);
  ushort4 b;
  b.x = f2bf(v.x); b.y = f2bf(v.y); b.z = f2bf(v.z); b.w = f2bf(v.w);
  const int boff = (lane * 8) ^ ((row & 7) << 4);
  *reinterpret_cast<ushort4*>((char*)Cbf + (size_t)row * 512 + boff) = b;
  float sq = v.x * v.x + v.y * v.y + v.z * v.z + v.w * v.w;
#pragma unroll
  for (int o = 32; o; o >>= 1) sq += __shfl_xor(sq, o);
  if (lane == 0) csq[row] = sq;
}

// Fused: out[m][n] = ||F_m||^2 + ||C_n||^2 - 2*F_m.C_n
// SMALL blocks (64 F-rows x 64 centers) -> grid 4096 >> residency (~1024):
// ~4 dispatch rounds so later blocks' A-reads overlap earlier blocks' writes
// (breaks chip-wide read-phase/write-phase alignment, the r9/r11 limiter).
// Per block: B-slice 32KB staged once (gload_lds, pre-swizzled source,
// read-XOR unswizzle [r11-verified]); A direct-to-registers in 2 half-
// batches (VGPR cap); ONE barrier; barrier-free MFMA loop, stores per-ni.
__global__ __launch_bounds__(256, 4) void dist_fused(
    const float* __restrict__ F, const unsigned short* __restrict__ Cbf,
    const float* __restrict__ csq, float* __restrict__ out, int M, int N) {
  __shared__ __align__(16) char Bs[64 * 512];   // 32 KB: 64 centers x full K

  const int t = threadIdx.x;
  const int w = t >> 6, l = t & 63;
  const int rl = l & 15, kh = l >> 4;
  const int amask = (rl & 7) << 4;    // B read-side XOR (LDS row%8 == rl%8)

  // XCD swizzle: XCD x (= bid&7, round-robin dispatch) gets works
  // [x*512, x*512+512) in order -> 8 consecutive blocks on one XCD are the
  // 8 n-groups of ONE m-panel (panel read HBM once, L2 serves the rest).
  const int work = (blockIdx.x & 7) * 512 + (blockIdx.x >> 3);
  const int m0 = (work >> 3) * 64;
  const int n0 = (work & 7) * 64;
  const int mrow = m0 + w * 16 + rl;

  // ---- B staging: 8 rounds x 8 rows x 512B. Source LINEAR (Cbf is
  // pre-swizzled in memory); LDS dest linear (wave base + lane*16).
  const int srow = t >> 5;            // 0..7
  const int scol = (t & 31) * 16;     // 0..496
  const char* Bsrc = (const char*)Cbf + (size_t)(n0 + srow) * 512 + scol;
#pragma unroll
  for (int j = 0; j < 8; ++j)
    gload16(Bsrc + (size_t)j * 4096, (char*)Bs + j * 4096 + t * 16);

  // ---- A: direct to registers, two half-batches of 8 loads (VGPR cap).
  const char* Arow = (const char*)F + (size_t)mrow * 1024 + kh * 32;
  bf16x8 af[8];
  float rsq = 0.f;
#pragma unroll
  for (int h = 0; h < 2; ++h) {
    f32x4 a0[4], a1[4];
#pragma unroll
    for (int k = 0; k < 4; ++k) {
      a0[k] = *reinterpret_cast<const f32x4*>(Arow + (h * 4 + k) * 128);
      a1[k] = *reinterpret_cast<const f32x4*>(Arow + (h * 4 + k) * 128 + 16);
    }
#pragma unroll
    for (int k = 0; k < 4; ++k) {
      const f32x4 x = a0[k], y = a1[k];
      rsq += x[0] * x[0] + x[1] * x[1] + x[2] * x[2] + x[3] * x[3] +
             y[0] * y[0] + y[1] * y[1] + y[2] * y[2] + y[3] * y[3];
      bf16x8 v;
      v[0] = (short)f2bf(x[0]); v[1] = (short)f2bf(x[1]);
      v[2] = (short)f2bf(x[2]); v[3] = (short)f2bf(x[3]);
      v[4] = (short)f2bf(y[0]); v[5] = (short)f2bf(y[1]);
      v[6] = (short)f2bf(y[2]); v[7] = (short)f2bf(y[3]);
      af[h * 4 + k] = v;
      asm volatile("" : "+v"(af[h * 4 + k]));   // block rematerialization
    }
  }
  float fv = rsq;
  fv += __shfl_xor(fv, 16);
  fv += __shfl_xor(fv, 32);   // every lane: full ||F_row||^2

  // All 24 VMEM ops (8 B-stage + 16 A) retired in-order by the A-cvt waits;
  // explicit drain + the ONLY barrier: every wave's B-staging visible.
  asm volatile("s_waitcnt vmcnt(0)" ::: "memory");
  __builtin_amdgcn_s_barrier();
  asm volatile("" ::: "memory");

  // ---- Barrier-free compute: 4 n-tiles x 8 K-steps; stores spread per-ni.
#pragma unroll
  for (int ni = 0; ni < 4; ++ni) {
    f32x4 acc = (f32x4){0.f, 0.f, 0.f, 0.f};
#pragma unroll
    for (int kt = 0; kt < 8; ++kt) {
      const bf16x8 bfr = *reinterpret_cast<const bf16x8*>(
          (const char*)Bs + (ni * 16 + rl) * 512 + ((kt * 64 + kh * 16) ^ amask));
      // SWAPPED operands: D col = F-row (rl), D row = center (kh*4+reg). [r7-r11]
      acc = __builtin_amdgcn_mfma_f32_16x16x32_bf16(bfr, af[kt], acc, 0, 0, 0);
    }
    const int nloc = n0 + ni * 16 + kh * 4;
    const float4 cs4 = *reinterpret_cast<const float4*>(&csq[nloc]);  // broadcast, L2-hot
    float4 v;
    v.x = fv + cs4.x - 2.0f * acc[0];
    v.y = fv + cs4.y - 2.0f * acc[1];
    v.z = fv + cs4.z - 2.0f * acc[2];
    v.w = fv + cs4.w - 2.0f * acc[3];
    *reinterpret_cast<float4*>(&out[(size_t)mrow * N + nloc]) = v;
  }
}

extern "C" void kernel_launch(void* const* d_in, const int* in_sizes, int n_in,
                              void* d_out, int out_size, void* d_ws, size_t ws_size,
                              hipStream_t stream) {
  const float* F = (const float*)d_in[0];   // (16, 2048, 256) fp32
  const float* C = (const float*)d_in[1];   // (1, 512, 256) fp32
  float* out = (float*)d_out;               // (16, 2048, 512) fp32
  const int D = 256;
  const int M = in_sizes[0] / D;            // 32768
  const int N = in_sizes[1] / D;            // 512

  unsigned short* Cbf = (unsigned short*)d_ws;    // N*256 bf16 (128B-block swizzled)
  float* csq = (float*)(Cbf + (size_t)N * D);     // N fp32

  hipLaunchKernelGGL(prep_c, dim3(N / 4), dim3(256), 0, stream, C, Cbf, csq, N);
  const int nwg = (M / 64) * (N / 64);            // 4096, divisible by 8
  hipLaunchKernelGGL(dist_fused, dim3(nwg), dim3(256), 0, stream,
                     F, Cbf, csq, out, M, N);
}

// Round 14
// 42.390 us; speedup vs baseline: 1.2263x; 1.2263x over previous
//
#include <hip/hip_runtime.h>

typedef __attribute__((ext_vector_type(8))) short bf16x8;   // 8 bf16 (4 VGPRs)
typedef __attribute__((ext_vector_type(4))) float f32x4;

#define D_DIM 256   // feature dim (bf16 row = 512 B)
#define BM 128
#define BN 128
#define BK 64       // K-step in elements (128 B per row-chunk)

__device__ inline unsigned short f2bf(float f) {
  unsigned int u = __builtin_bit_cast(unsigned int, f);
  u += 0x7fffu + ((u >> 16) & 1u);     // round-to-nearest-even
  return (unsigned short)(u >> 16);
}

__device__ inline void gload16(const void* g, void* l) {
  __builtin_amdgcn_global_load_lds(
      (const __attribute__((address_space(1))) void*)g,
      (__attribute__((address_space(3))) void*)l, 16, 0, 0);
}

// One wave per row. Writes bf16 copy PRE-XOR-SWIZZLED (byte ^= (row&7)<<4,
// a permutation within each 128B sub-block of the 512B row) + exact fp32
// sum-of-squares. Rows [0,M) from F -> Abf/fsq; rows [M,M+K) from C -> Cbf/csq.
// [byte-identical to r6]
__global__ void prep_rows(const float* __restrict__ F, const float* __restrict__ C,
                          unsigned short* __restrict__ Abf, unsigned short* __restrict__ Cbf,
                          float* __restrict__ fsq, float* __restrict__ csq, int M) {
  const int w = threadIdx.x >> 6, lane = threadIdx.x & 63;
  int row = blockIdx.x * 4 + w;
  const float* src;
  unsigned short* dst;
  float* rsq;
  if (row < M) {
    src = F; dst = Abf; rsq = fsq;
  } else {
    row -= M;
    src = C; dst = Cbf; rsq = csq;
  }
  const float4 v = *reinterpret_cast<const float4*>(&src[(size_t)row * D_DIM + lane * 4]);
  ushort4 b;
  b.x = f2bf(v.x); b.y = f2bf(v.y); b.z = f2bf(v.z); b.w = f2bf(v.w);
  const int boff = (lane * 8) ^ ((row & 7) << 4);   // swizzled byte offset in 512B row
  *reinterpret_cast<ushort4*>((char*)dst + (size_t)row * 512 + boff) = b;
  float sq = v.x * v.x + v.y * v.y + v.z * v.z + v.w * v.w;
#pragma unroll
  for (int o = 32; o; o >>= 1) sq += __shfl_xor(sq, o);
  if (lane == 0) rsq[row] = sq;
}

// out[m][n] = fsq[m] + csq[n] - 2 * sum_d A[m][d]*B[n][d]
// r6 structure (counted-vmcnt dbuf, gload_lds, pre-swizzled source, read-XOR)
// with TWO changes: SWAPPED MFMA operands (D col = F-row rl, D row = center
// kh*4+reg [r7-r11 verified]) -> per-thread acc regs are 4 consecutive n ->
// 16x f32x4 NONTEMPORAL stores (evict-first, no L2/L3 write-allocate).
__global__ __launch_bounds__(256, 2) void dist_gemm(
    const unsigned short* __restrict__ A, const unsigned short* __restrict__ B,
    const float* __restrict__ fsq, const float* __restrict__ csq,
    float* __restrict__ out, int M, int N) {
  __shared__ __align__(16) char As[2][BM * 128];   // 2 x 16 KB
  __shared__ __align__(16) char Bs[2][BN * 128];   // 2 x 16 KB

  const int t = threadIdx.x;
  const int w = t >> 6, lane = t & 63;
  const int wr = w >> 1, wc = w & 1;          // wave -> 64x64 quadrant
  const int rl = lane & 15, kh = lane >> 4;   // fragment lane decomposition
  const int amask = (rl & 7) << 4;            // read-side XOR (row key: row&7 == rl&7)

  // Bijective XCD swizzle (1024 blocks, %8==0); n-tile fastest so the 4
  // blocks sharing an A m-panel run consecutively on the same XCD.
  const int nwg = gridDim.x;
  const int cpx = nwg >> 3;
  const int work = (blockIdx.x & 7) * cpx + (blockIdx.x >> 3);
  const int ntiles = N / BN;                  // 4
  const int n0 = (work % ntiles) * BN;
  const int m0 = (work / ntiles) * BM;

  // staging decomposition (thread-constant): 4 rounds x 32 rows, 16B/lane.
  // Source column LINEAR — memory is already swizzled; LDS dest linear.
  const int s_row = t >> 3;                   // 0..31
  const int s_cb = (t & 7) * 16;              // linear col byte in 128B chunk
  const char* Asrc = (const char*)A + (size_t)(m0 + s_row) * 512 + s_cb;
  const char* Bsrc = (const char*)B + (size_t)(n0 + s_row) * 512 + s_cb;
  // j-round advance: 32 rows * 512 B = 16384 B; K-step advance: 128 B.

  // prologue: stage kt=0 into buffer 0 (8 loads in flight)
#pragma unroll
  for (int j = 0; j < 4; ++j)
    gload16(Asrc + j * 16384, (char*)As[0] + j * 4096 + w * 1024);
#pragma unroll
  for (int j = 0; j < 4; ++j)
    gload16(Bsrc + j * 16384, (char*)Bs[0] + j * 4096 + w * 1024);

  // norm-term prefetch for the SWAPPED epilogue layout:
  // lane holds m = m0+wr*64+mi*16+rl (scalar fsq) and 4 consecutive n
  // starting at n0+wc*64+ni*16+kh*4 (float4 csq). Both L2/L3-hot.
  float fvm[4];
#pragma unroll
  for (int mi = 0; mi < 4; mi++)
    fvm[mi] = fsq[m0 + wr * 64 + mi * 16 + rl];
  f32x4 cs4[4];
#pragma unroll
  for (int ni = 0; ni < 4; ni++)
    cs4[ni] = *reinterpret_cast<const f32x4*>(&csq[n0 + wc * 64 + ni * 16 + kh * 4]);

  f32x4 acc[4][4];
#pragma unroll
  for (int i = 0; i < 4; i++)
#pragma unroll
    for (int j = 0; j < 4; j++) acc[i][j] = (f32x4){0.f, 0.f, 0.f, 0.f};

#pragma unroll
  for (int kt = 0; kt < 4; ++kt) {
    const int cur = kt & 1;
    if (kt < 3) {
      const int nxt = cur ^ 1;
      // issue next K-tile's loads; they stay in flight across the barrier
#pragma unroll
      for (int j = 0; j < 4; ++j)
        gload16(Asrc + (kt + 1) * 128 + j * 16384, (char*)As[nxt] + j * 4096 + w * 1024);
#pragma unroll
      for (int j = 0; j < 4; ++j)
        gload16(Bsrc + (kt + 1) * 128 + j * 16384, (char*)Bs[nxt] + j * 4096 + w * 1024);
      asm volatile("s_waitcnt vmcnt(8)" ::: "memory");   // current tile landed; next 8 in flight
    } else {
      asm volatile("s_waitcnt vmcnt(0)" ::: "memory");   // last tile: drain
    }
    __builtin_amdgcn_s_barrier();
    asm volatile("" ::: "memory");   // pin ds_reads after the barrier (compiler fence)

#pragma unroll
    for (int kk = 0; kk < 2; ++kk) {
      const int soff = (kk * 64 + kh * 16) ^ amask;
      bf16x8 af[4], bfr[4];
#pragma unroll
      for (int mi = 0; mi < 4; mi++)
        af[mi] = *reinterpret_cast<const bf16x8*>(
            (const char*)As[cur] + (wr * 64 + mi * 16 + rl) * 128 + soff);
#pragma unroll
      for (int ni = 0; ni < 4; ni++)
        bfr[ni] = *reinterpret_cast<const bf16x8*>(
            (const char*)Bs[cur] + (wc * 64 + ni * 16 + rl) * 128 + soff);
      // SWAPPED operand order: D col (lane&15) = F-row, D row (kh*4+reg) = center.
#pragma unroll
      for (int mi = 0; mi < 4; mi++)
#pragma unroll
        for (int ni = 0; ni < 4; ni++)
          acc[mi][ni] = __builtin_amdgcn_mfma_f32_16x16x32_bf16(
              bfr[ni], af[mi], acc[mi][ni], 0, 0, 0);
    }
    __builtin_amdgcn_s_barrier();    // all waves done reading buf[cur] before restage
    asm volatile("" ::: "memory");   // pin next iteration's staging after the barrier
  }

  // Epilogue (swapped layout): m = m0+wr*64+mi*16+rl (per-lane), 4 consecutive
  // n per (ni) -> f32x4 NONTEMPORAL stores (no L2/L3 allocation).
#pragma unroll
  for (int mi = 0; mi < 4; mi++) {
    const int m = m0 + wr * 64 + mi * 16 + rl;
#pragma unroll
    for (int ni = 0; ni < 4; ni++) {
      const int n = n0 + wc * 64 + ni * 16 + kh * 4;
      f32x4 v;
      v[0] = fvm[mi] + cs4[ni][0] - 2.0f * acc[mi][ni][0];
      v[1] = fvm[mi] + cs4[ni][1] - 2.0f * acc[mi][ni][1];
      v[2] = fvm[mi] + cs4[ni][2] - 2.0f * acc[mi][ni][2];
      v[3] = fvm[mi] + cs4[ni][3] - 2.0f * acc[mi][ni][3];
      __builtin_nontemporal_store(
          v, reinterpret_cast<f32x4*>(&out[(size_t)m * N + n]));
    }
  }
}

extern "C" void kernel_launch(void* const* d_in, const int* in_sizes, int n_in,
                              void* d_out, int out_size, void* d_ws, size_t ws_size,
                              hipStream_t stream) {
  const float* F = (const float*)d_in[0];   // (16, 2048, 256) fp32
  const float* C = (const float*)d_in[1];   // (1, 512, 256) fp32
  float* out = (float*)d_out;               // (16, 2048, 512) fp32
  const int M = in_sizes[0] / D_DIM;        // 32768
  const int N = in_sizes[1] / D_DIM;        // 512

  unsigned short* Abf = (unsigned short*)d_ws;            // M*256 bf16 (swizzled)
  unsigned short* Cbf = Abf + (size_t)M * D_DIM;          // N*256 bf16 (swizzled)
  float* fsq = (float*)(Cbf + (size_t)N * D_DIM);         // M fp32
  float* csq = fsq + M;                                   // N fp32

  hipLaunchKernelGGL(prep_rows, dim3((M + N) / 4), dim3(256), 0, stream,
                     F, C, Abf, Cbf, fsq, csq, M);
  const int nwg = (M / BM) * (N / BN);      // 1024, divisible by 8
  hipLaunchKernelGGL(dist_gemm, dim3(nwg), dim3(256), 0, stream,
                     Abf, Cbf, fsq, csq, out, M, N);
}